// Round 9
// baseline (213.829 us; speedup 1.0000x reference)
//
#include <hip/hip_runtime.h>
#include <hip/hip_bf16.h>

#define B_ 2
#define C_ 20000
#define H_ 64
#define M_ 8
#define E_ 200000
#define P_ 3
#define EPS_ 1e-12f
#define ET_ (E_ / 64)   // edge tiles per batch = 3125

typedef __attribute__((ext_vector_type(8))) short short8;
typedef __attribute__((ext_vector_type(4))) float float4v;

// ---- fast approx math (bf16-precision pipeline; absmax tol is huge) -------
__device__ __forceinline__ float rcp_(float x)  { return __builtin_amdgcn_rcpf(x); }
__device__ __forceinline__ float sqrt_(float x) { return __builtin_amdgcn_sqrtf(x); }
__device__ __forceinline__ float silu_(float x) {
    return x * __builtin_amdgcn_rcpf(1.f + __expf(-x));
}
__device__ __forceinline__ float tanh_(float x) {
    // tanh(x) = 1 - 2/(e^{2x}+1); saturates correctly for |x| large
    float e = __expf(2.f * x);
    return 1.f - 2.f * __builtin_amdgcn_rcpf(e + 1.f);
}
__device__ __forceinline__ unsigned short f2b(float f) {
    unsigned u = __float_as_uint(f);
    unsigned r = (u + 0x7FFF + ((u >> 16) & 1)) >> 16;   // RNE fp32->bf16
    return (unsigned short)r;
}
__device__ __forceinline__ float b2f(unsigned short h) {
    return __uint_as_float(((unsigned)h) << 16);
}
__device__ __forceinline__ unsigned pk2u(float a, float b) {
    __hip_bfloat162 h = __float22bfloat162_rn(make_float2(a, b)); // v_cvt_pk_bf16_f32
    unsigned u; __builtin_memcpy(&u, &h, sizeof(u)); return u;
}
__device__ __forceinline__ float lo16f(unsigned u) { return __uint_as_float(u << 16); }
__device__ __forceinline__ float hi16f(unsigned u) { return __uint_as_float(u & 0xFFFF0000u); }

// bf16 B-fragment-swizzled weights (K multiples of 32; W1 rows 128..131 on VALU)
#define W1S_OFF 0
#define W2S_OFF 8192
#define P1S_OFF 12288
#define U1S_OFF 16384
#define U2S_OFF 24576
#define WBUF_ELEMS 28672

// combo_kernel block ranges (all parts independent)
#define NB_PREP  120                     // 28672 weight-frag elems
#define NB_FEATB 2500                    // B*C*64/4 = 640000 threads
#define NB_DESC  157                     // ceil(B*C/256)
#define NB_HIST  782                     // ceil(E/256)
#define NB_ZAGG  2500                    // B*C*64 floats / (256*4) zero-fill
#define NB_PCOPY 118                     // ceil(B*C*3/4 / 256) pos -> out_pos
#define NB_COMBO (NB_PREP + NB_FEATB + NB_DESC + NB_HIST + NB_ZAGG + NB_PCOPY)

// packed descriptor row: 32 uints = 128 B, ONE cache line per (b,cell):
//   u[0..15]  : 8 nodes as uint2{pk(x,y), pk(z,m)}   (bf16)
//   u[16..19] : centroid float4 (cx,cy,cz,summ)      (fp32)
//   u[20..23] : own pos float4 (px,py,pz,0)          (fp32)
//   u[24..31] : pad

__global__ __launch_bounds__(256) void combo_kernel(
    const float* __restrict__ W1, const float* __restrict__ W2,
    const float* __restrict__ P1, const float* __restrict__ U1,
    const float* __restrict__ U2, unsigned short* __restrict__ wbuf,
    const float* __restrict__ feat, unsigned short* __restrict__ featb,
    const float* __restrict__ pos, const int* __restrict__ cni,
    const float* __restrict__ mask, unsigned* __restrict__ descp,
    const int* __restrict__ ei, int* __restrict__ cnt,
    float* __restrict__ aggf, float* __restrict__ out_pos)
{
    const int bid = blockIdx.x;
    if (bid < NB_PREP) {
        // ---- weight swizzle -> bf16 B-fragments
        int t = bid * 256 + threadIdx.x;
        if (t >= WBUF_ELEMS) return;
        const float* W; int e;
        if (t < W2S_OFF)      { W = W1; e = t; }
        else if (t < U1S_OFF) { W = (t < P1S_OFF) ? W2 : P1; e = (t < P1S_OFF) ? t - W2S_OFF : t - P1S_OFF; }
        else if (t < U2S_OFF) { W = U1; e = t - U1S_OFF; }
        else                  { W = U2; e = t - U2S_OFF; }
        int j = e & 7, lane = (e >> 3) & 63, nt = (e >> 9) & 3, kk = e >> 11;
        int k = kk * 32 + ((lane >> 4) * 8) + j;
        int n = nt * 16 + (lane & 15);
        wbuf[t] = f2b(W[k * 64 + n]);
    } else if (bid < NB_PREP + NB_FEATB) {
        // ---- features -> bf16 cache (coalesced)
        int t = (bid - NB_PREP) * 256 + threadIdx.x;   // < 640000 exactly
        float4 v = *(const float4*)&feat[(size_t)t * 4];
        *(uint2*)&featb[(size_t)t * 4] = make_uint2(pk2u(v.x, v.y), pk2u(v.z, v.w));
    } else if (bid < NB_PREP + NB_FEATB + NB_DESC) {
        // ---- per-(b,cell) packed descriptor (one 128B line)
        int tid = (bid - NB_PREP - NB_FEATB) * 256 + threadIdx.x;
        if (tid >= B_ * C_) return;
        int b = tid / C_, c = tid - b * C_;
        const float* pb = pos + (size_t)b * C_ * P_;
        unsigned* D = descp + (size_t)tid * 32;
        int4 n0 = *(const int4*)&cni[c*8];
        int4 n1 = *(const int4*)&cni[c*8 + 4];
        float4 m0 = *(const float4*)&mask[c*8];
        float4 m1 = *(const float4*)&mask[c*8 + 4];
        int ni[8] = {n0.x, n0.y, n0.z, n0.w, n1.x, n1.y, n1.z, n1.w};
        float mm[8] = {m0.x, m0.y, m0.z, m0.w, m1.x, m1.y, m1.z, m1.w};
        float sx = 0.f, sy = 0.f, sz = 0.f, sm = 0.f;
        #pragma unroll
        for (int m = 0; m < 8; ++m) {
            float x = pb[ni[m]*3+0], y = pb[ni[m]*3+1], z = pb[ni[m]*3+2];
            ((uint2*)D)[m] = make_uint2(pk2u(x, y), pk2u(z, mm[m]));
            sx += x * mm[m]; sy += y * mm[m]; sz += z * mm[m]; sm += mm[m];
        }
        float inv = rcp_(fmaxf(sm, EPS_));
        *(float4*)(D + 16) = make_float4(sx * inv, sy * inv, sz * inv, sm);
        *(float4*)(D + 20) = make_float4(pb[c*3+0], pb[c*3+1], pb[c*3+2], 0.f);
    } else if (bid < NB_PREP + NB_FEATB + NB_DESC + NB_HIST) {
        // ---- dst histogram
        int e = (bid - NB_PREP - NB_FEATB - NB_DESC) * 256 + threadIdx.x;
        if (e >= E_) return;
        atomicAdd(&cnt[ei[E_ + e]], 1);
    } else if (bid < NB_PREP + NB_FEATB + NB_DESC + NB_HIST + NB_ZAGG) {
        // ---- zero aggf (consumed only by edge_kernel, later in stream)
        int t = (bid - NB_PREP - NB_FEATB - NB_DESC - NB_HIST) * 256 + threadIdx.x;
        *(float4*)&aggf[(size_t)t * 4] = make_float4(0.f, 0.f, 0.f, 0.f);
    } else {
        // ---- out_pos = pos (base for edge_kernel's atomics)
        int t = (bid - NB_PREP - NB_FEATB - NB_DESC - NB_HIST - NB_ZAGG) * 256 + threadIdx.x;
        if (t >= (B_ * C_ * P_) / 4) return;
        *(float4*)&out_pos[(size_t)t * 4] = *(const float4*)&pos[(size_t)t * 4];
    }
}

// ---------------------------------------------------------------------------
// alloc: wave-scan + one atomic bump per wave -> cursor (segment order free)
// ---------------------------------------------------------------------------
__global__ __launch_bounds__(256) void alloc_kernel(
    const int* __restrict__ cnt, int* __restrict__ cursor, int* __restrict__ total)
{
    int idx = blockIdx.x * 256 + threadIdx.x;
    int lane = threadIdx.x & 63;
    int v = (idx < C_) ? cnt[idx] : 0;
    int inc = v;
    #pragma unroll
    for (int s = 1; s < 64; s <<= 1) {
        int n = __shfl_up(inc, s);
        if (lane >= s) inc += n;
    }
    int wtot = __shfl(inc, 63);
    int base = 0;
    if (lane == 0) base = atomicAdd(total, wtot);
    base = __shfl(base, 0);
    if (idx < C_) cursor[idx] = base + inc - v;
}

// ---------------------------------------------------------------------------
// scatter: plain dst-sort (cheap; geometry in post-sort geom_kernel)
// ---------------------------------------------------------------------------
__global__ __launch_bounds__(256) void scatter_kernel(
    const int* __restrict__ ei, int* __restrict__ cursor, int2* __restrict__ sed)
{
    int e = blockIdx.x * 256 + threadIdx.x;
    if (e >= E_) return;
    int s = ei[e], d = ei[E_ + e];
    int slot = atomicAdd(&cursor[d], 1);
    sed[slot] = make_int2(s, d);
}

// ---------------------------------------------------------------------------
// geom: per-(batch, sorted-slot) 8x8 distance field from the PACKED one-line
// descriptor: each cell gather = exactly 1 cache line. Sorted dst side
// additionally coalesces across the wave. Pure TLP, latency-tolerant.
// ---------------------------------------------------------------------------
__global__ __launch_bounds__(256) void geom_kernel(
    const int2* __restrict__ sed, const unsigned* __restrict__ descp,
    float4* __restrict__ ivA, float4* __restrict__ ivR)
{
    int idx = blockIdx.x * 256 + threadIdx.x;     // idx = b*E + slot
    if (idx >= B_ * E_) return;
    int b = idx / E_, slot = idx - b * E_;
    int2 sd = sed[slot];
    const unsigned* Ds = descp + ((size_t)b * C_ + sd.x) * 32;
    const unsigned* Dd = descp + ((size_t)b * C_ + sd.y) * 32;

    // issue all loads up front (independent)
    uint2 spk[8], dpk[8];
    #pragma unroll
    for (int i = 0; i < 8; ++i) { spk[i] = ((const uint2*)Ds)[i]; dpk[i] = ((const uint2*)Dd)[i]; }
    float4 Sc = *(const float4*)(Ds + 16), Dc = *(const float4*)(Dd + 16);
    float4 Sp = *(const float4*)(Ds + 20), Dp = *(const float4*)(Dd + 20);

    const float INFV = __builtin_inff();
    float4 S[8]; float rowmin[8];
    #pragma unroll
    for (int i = 0; i < 8; ++i) {
        S[i] = make_float4(lo16f(spk[i].x), hi16f(spk[i].x),
                           lo16f(spk[i].y), hi16f(spk[i].y));
        rowmin[i] = INFV;
    }
    float pair = 0.f, hyx = 0.f;
    #pragma unroll
    for (int j = 0; j < 8; ++j) {
        float djx = lo16f(dpk[j].x), djy = hi16f(dpk[j].x);
        float djz = lo16f(dpk[j].y), djw = hi16f(dpk[j].y);
        float colmin = INFV;
        #pragma unroll
        for (int i = 0; i < 8; ++i) {
            float dx = S[i].x - djx, dy = S[i].y - djy, dz = S[i].z - djz;
            float dd = sqrt_(dx*dx + dy*dy + dz*dz + EPS_);
            pair += dd * S[i].w * djw;
            rowmin[i] = (djw    > 0.f) ? fminf(rowmin[i], dd) : rowmin[i];
            colmin    = (S[i].w > 0.f) ? fminf(colmin, dd)    : colmin;
        }
        hyx = fmaxf(hyx, (djw > 0.f) ? colmin : 0.f);
    }
    float hxy = 0.f;
    #pragma unroll
    for (int i = 0; i < 8; ++i)
        hxy = fmaxf(hxy, (S[i].w > 0.f) ? rowmin[i] : 0.f);
    float cdx = Sc.x - Dc.x, cdy = Sc.y - Dc.y, cdz = Sc.z - Dc.z;
    float rx = Sp.x - Dp.x, ry = Sp.y - Dp.y, rz = Sp.z - Dp.z;
    ivA[idx] = make_float4(sqrt_(rx*rx + ry*ry + rz*rz), pair,
                           sqrt_(cdx*cdx + cdy*cdy + cdz*cdz), fmaxf(hxy, hyx));
    ivR[idx] = make_float4(rx, ry, rz, 0.f);
}

// ---------------------------------------------------------------------------
// Edge kernel (geometry-free): stage X -> 3 MFMA MLP stages -> in-wave
// segmented aggregation. NEW: wave-private segments (true start AND end
// inside this wave's 16-row strip, detected via 64-lane dst ballot over the
// whole dst-sorted tile) use plain vector STORES into the pre-zeroed aggf
// instead of 64-wide atomicAdds -> cuts L2 atomic RMW volume ~40-50%.
// ---------------------------------------------------------------------------
__global__ __launch_bounds__(256, 8) void edge_kernel(
    const unsigned short* __restrict__ featb,
    const int2* __restrict__ sed,
    const float4* __restrict__ ivA, const float4* __restrict__ ivR,
    const unsigned short* __restrict__ wbuf, const float* __restrict__ W1,
    const float* __restrict__ b1, const float* __restrict__ b2,
    const float* __restrict__ pb1, const float* __restrict__ P2,
    const float* __restrict__ pb2,
    float* __restrict__ aggf, float* __restrict__ out_pos)
{
    __shared__ unsigned short lds[4 * 2304];   // 18432 B

    const int tid  = threadIdx.x;
    const int w    = tid >> 6;
    const int lane = tid & 63;
    const int q    = lane >> 4;
    const int l16  = lane & 15;
    const int w16  = w * 16;

    // bijective XCD swizzle (nwg = 6250; m204 variant)
    const int bidr = blockIdx.x;
    const int xcd  = bidr & 7, kblk = bidr >> 3;
    const int qq   = (B_ * ET_) >> 3, rr_ = (B_ * ET_) & 7;
    const int tile = (xcd < rr_ ? xcd * (qq + 1) : rr_ * (qq + 1) + (xcd - rr_) * qq) + kblk;

    const int b    = tile / ET_;
    const int i0   = (tile - b * ET_) * 64;
    const unsigned short* fb = featb + (size_t)b * C_ * H_;

    // ---- independent prefetches: invariants (per-row broadcast) + rel ------
    float4 iva[4];
    #pragma unroll
    for (int i = 0; i < 4; ++i)
        iva[i] = ivA[(size_t)b * E_ + i0 + w16 + q*4 + i];
    const float4 relv = ivR[(size_t)b * E_ + i0 + w16 + l16];

    const int2 sd  = sed[i0 + lane];
    const int s_l  = sd.x;
    const int d_l  = sd.y;
    const int dg   = __shfl(d_l, w16 + l16);   // dst of row l16

    unsigned short* Xw = lds + w * 2304;
    unsigned short* Hw = Xw;          // alias: X dead before H written (dep chain)
    unsigned short* Mw = Xw + 1152;   // disjoint from Hw

    // ================= stage X = [h_src | h_dst] from bf16 cache =============
    const int rr4 = lane >> 4, c4 = lane & 15;
    #pragma unroll
    for (int it = 0; it < 4; ++it) {
        int rloc = it * 4 + rr4;
        int r = w16 + rloc;
        int sr = __shfl(s_l, r);
        int dr = __shfl(d_l, r);
        uint2 vs = *(const uint2*)&fb[(size_t)sr * 64 + c4 * 4];
        uint2 vd = *(const uint2*)&fb[(size_t)dr * 64 + c4 * 4];
        *(uint2*)&Xw[rloc*136 + c4*4]      = vs;
        *(uint2*)&Xw[rloc*136 + 64 + c4*4] = vd;
    }

    // ================= layer 1: bias + fp32 invariant tail folded into init ==
    float4v acc[4];
    #pragma unroll
    for (int nt = 0; nt < 4; ++nt) {
        float bv = b1[nt*16 + l16];
        float wa = W1[128*64 + nt*16 + l16];
        float wb = W1[129*64 + nt*16 + l16];
        float wc = W1[130*64 + nt*16 + l16];
        float wd = W1[131*64 + nt*16 + l16];
        #pragma unroll
        for (int i = 0; i < 4; ++i)
            acc[nt][i] = bv + iva[i].x*wa + iva[i].y*wb
                            + iva[i].z*wc + iva[i].w*wd;
    }
    #pragma unroll
    for (int kk = 0; kk < 4; ++kk) {
        short8 a = *(const short8*)&Xw[l16*136 + kk*32 + q*8];
        #pragma unroll
        for (int nt = 0; nt < 4; ++nt) {
            short8 bf = *(const short8*)&wbuf[W1S_OFF + (((kk*4 + nt)*64) + lane) * 8];
            acc[nt] = __builtin_amdgcn_mfma_f32_16x16x32_bf16(a, bf, acc[nt], 0, 0, 0);
        }
    }
    // packed bf16 epilogue: row-pairs share a v_cvt_pk_bf16_f32
    #pragma unroll
    for (int nt = 0; nt < 4; ++nt)
        #pragma unroll
        for (int i = 0; i < 4; i += 2) {
            unsigned u = pk2u(silu_(acc[nt][i]), silu_(acc[nt][i+1]));
            Hw[(q*4 + i)*72     + nt*16 + l16] = (unsigned short)u;
            Hw[(q*4 + i + 1)*72 + nt*16 + l16] = (unsigned short)(u >> 16);
        }

    // ================= layer 2 -> messages ===================================
    float4v mac[4];
    #pragma unroll
    for (int nt = 0; nt < 4; ++nt) {
        float bv = b2[nt*16 + l16];
        mac[nt] = (float4v){bv, bv, bv, bv};
    }
    #pragma unroll
    for (int kk = 0; kk < 2; ++kk) {
        short8 a = *(const short8*)&Hw[l16*72 + kk*32 + q*8];
        #pragma unroll
        for (int nt = 0; nt < 4; ++nt) {
            short8 bf = *(const short8*)&wbuf[W2S_OFF + (((kk*4 + nt)*64) + lane) * 8];
            mac[nt] = __builtin_amdgcn_mfma_f32_16x16x32_bf16(a, bf, mac[nt], 0, 0, 0);
        }
    }
    #pragma unroll
    for (int nt = 0; nt < 4; ++nt)
        #pragma unroll
        for (int i = 0; i < 4; i += 2) {
            unsigned u = pk2u(mac[nt][i], mac[nt][i+1]);
            Mw[(q*4 + i)*72     + nt*16 + l16] = (unsigned short)u;
            Mw[(q*4 + i + 1)*72 + nt*16 + l16] = (unsigned short)(u >> 16);
        }

    // ================= gate: wt = tanh(silu(M @ P1 + pb1) @ P2 + pb2) ========
    float4v gac[4];
    #pragma unroll
    for (int nt = 0; nt < 4; ++nt) {
        float bv = pb1[nt*16 + l16];
        gac[nt] = (float4v){bv, bv, bv, bv};
    }
    #pragma unroll
    for (int kk = 0; kk < 2; ++kk) {
        short8 a = *(const short8*)&Mw[l16*72 + kk*32 + q*8];
        #pragma unroll
        for (int nt = 0; nt < 4; ++nt) {
            short8 bf = *(const short8*)&wbuf[P1S_OFF + (((kk*4 + nt)*64) + lane) * 8];
            gac[nt] = __builtin_amdgcn_mfma_f32_16x16x32_bf16(a, bf, gac[nt], 0, 0, 0);
        }
    }
    float p2v[4];
    #pragma unroll
    for (int nt = 0; nt < 4; ++nt) p2v[nt] = P2[nt*16 + l16];
    const float pb2v = pb2[0];

    #pragma unroll
    for (int i = 0; i < 4; ++i) {
        float p = 0.f;
        #pragma unroll
        for (int nt = 0; nt < 4; ++nt) p += silu_(gac[nt][i]) * p2v[nt];
        p += __shfl_xor(p, 8);
        p += __shfl_xor(p, 4);
        p += __shfl_xor(p, 2);
        p += __shfl_xor(p, 1);
        float wt = tanh_(p + pb2v);
        // store wt in spare columns 64..65 of the message row (fp32-aligned)
        if (l16 == 0) *(float*)&Mw[(q*4 + i)*72 + 64] = wt;
    }

    // ================= in-wave segmented aggregation =========================
    // Pre-load all 16 message rows (independent LDS reads) + per-row gate.
    float mrow[16];
    #pragma unroll
    for (int rr = 0; rr < 16; ++rr) mrow[rr] = b2f(Mw[rr*72 + lane]);
    float wtl = *(const float*)&Mw[l16*72 + 64];   // lane l16 holds row l16's wt

    float* aggB = aggf + (size_t)b * C_ * 64;
    float* opB  = out_pos + (size_t)b * C_ * 3;

    // full-tile (64-row) boundary ballot: bit l set => segment ends at row l.
    // Row 63 is never a TRUE end (next tile may continue the same dst).
    int dnx = __shfl(d_l, (lane + 1) & 63);
    bool bf64 = (lane == 63) || (d_l != dnx);
    unsigned long long bm64t = __ballot(bf64) & 0x7FFFFFFFFFFFFFFFull;

    // this wave's strip mask (force flush at strip row 15)
    unsigned mask16 = (unsigned)((bm64t >> w16) & 0xFFFFull) | 0x8000u;
    // does the strip's first segment have a TRUE start? (boundary at w16-1)
    const bool head_true = (w16 > 0) && ((bm64t >> (w16 - 1)) & 1ull);

    // distance from row l16 to its segment head (within strip, for the scan)
    unsigned below = mask16 & ((1u << l16) - 1u);
    int dist = l16 - (below ? (31 - __clz((int)below)) : -1) - 1;

    // ---- position update: segmented inclusive scan, per-segment atomics ----
    {
        float sx = wtl * relv.x, sy = wtl * relv.y, sz = wtl * relv.z;
        #pragma unroll
        for (int s = 1; s < 16; s <<= 1) {
            float tx = __shfl_up(sx, s);
            float ty = __shfl_up(sy, s);
            float tz = __shfl_up(sz, s);
            if (dist >= s) { sx += tx; sy += ty; sz += tz; }
        }
        bool bflag = (mask16 >> l16) & 1u;
        if (bflag && q == 0) {          // ~2.6 lanes/wave, 3 atomics each
            float* p = &opB[(size_t)dg * 3];
            atomicAdd(p + 0, sx);
            atomicAdd(p + 1, sy);
            atomicAdd(p + 2, sz);
        }
    }

    // ---- message aggregation: accumulate + flush; private segs use STORES --
    float colacc = 0.f;
    int prev = -1;
    #pragma unroll
    for (int rr = 0; rr < 16; ++rr) {
        colacc += mrow[rr];
        if (mask16 & (1u << rr)) {                         // wave-uniform
            int dseg = __builtin_amdgcn_readlane(dg, rr);  // row rr lives in lane rr
            bool tend   = (bm64t >> (w16 + rr)) & 1ull;    // true segment end here
            bool tstart = (prev >= 0) || head_true;        // true segment start in strip
            if (tend && tstart)
                aggB[(size_t)dseg * 64 + lane] = colacc;   // private: plain store
            else
                atomicAdd(&aggB[(size_t)dseg * 64 + lane], colacc);
            colacc = 0.f;
            prev = rr;
        }
    }
}

// ---------------------------------------------------------------------------
// Node update via MFMA, barrier-free wave-private strips.
// X = [featb | agg/max(deg,1)]; out = b2f(featb) + MLP(X)  (residual from the
// bf16 cache -> drops the 10.24 MB fp32 feat re-read; rounding << tolerance)
// ---------------------------------------------------------------------------
__global__ __launch_bounds__(256, 8) void node_kernel(
    const unsigned short* __restrict__ featb,
    const float* __restrict__ aggf, const float* __restrict__ deg,
    const unsigned short* __restrict__ wbuf,
    const float* __restrict__ ub1, const float* __restrict__ ub2,
    float* __restrict__ out_feat)
{
    __shared__ unsigned short lds[4 * 2304];

    const int tid  = threadIdx.x;
    const int w    = tid >> 6;
    const int lane = tid & 63;
    const int q    = lane >> 4;
    const int l16  = lane & 15;
    const int g0   = blockIdx.x * 64;

    unsigned short* Xw = lds + w * 2304;
    unsigned short* Hw = Xw;          // alias: X dead before H written

    const int rr4 = lane >> 4, c4 = lane & 15;
    #pragma unroll
    for (int it = 0; it < 4; ++it) {
        int rloc = it * 4 + rr4;
        int g = g0 + w*16 + rloc;
        int gc = (g >= C_) ? g - C_ : g;
        float sc = rcp_(fmaxf(deg[gc], 1.f));
        uint2  vf = *(const uint2*)&featb[(size_t)g * 64 + c4 * 4];
        float4 va = *(const float4*)&aggf[(size_t)g * 64 + c4 * 4];
        *(uint2*)&Xw[rloc*136 + c4*4]      = vf;
        *(uint2*)&Xw[rloc*136 + 64 + c4*4] =
            make_uint2(pk2u(va.x*sc, va.y*sc), pk2u(va.z*sc, va.w*sc));
    }

    float4v acc[4];
    #pragma unroll
    for (int nt = 0; nt < 4; ++nt) {
        float bv = ub1[nt*16 + l16];
        acc[nt] = (float4v){bv, bv, bv, bv};
    }
    #pragma unroll
    for (int kk = 0; kk < 4; ++kk) {
        short8 a = *(const short8*)&Xw[l16*136 + kk*32 + q*8];
        #pragma unroll
        for (int nt = 0; nt < 4; ++nt) {
            short8 bf = *(const short8*)&wbuf[U1S_OFF + (((kk*4 + nt)*64) + lane) * 8];
            acc[nt] = __builtin_amdgcn_mfma_f32_16x16x32_bf16(a, bf, acc[nt], 0, 0, 0);
        }
    }
    #pragma unroll
    for (int nt = 0; nt < 4; ++nt)
        #pragma unroll
        for (int i = 0; i < 4; i += 2) {
            unsigned u = pk2u(silu_(acc[nt][i]), silu_(acc[nt][i+1]));
            Hw[(q*4 + i)*72     + nt*16 + l16] = (unsigned short)u;
            Hw[(q*4 + i + 1)*72 + nt*16 + l16] = (unsigned short)(u >> 16);
        }

    float4v oac[4];
    #pragma unroll
    for (int nt = 0; nt < 4; ++nt) {
        float bv = ub2[nt*16 + l16];
        oac[nt] = (float4v){bv, bv, bv, bv};
    }
    #pragma unroll
    for (int kk = 0; kk < 2; ++kk) {
        short8 a = *(const short8*)&Hw[l16*72 + kk*32 + q*8];
        #pragma unroll
        for (int nt = 0; nt < 4; ++nt) {
            short8 bf = *(const short8*)&wbuf[U2S_OFF + (((kk*4 + nt)*64) + lane) * 8];
            oac[nt] = __builtin_amdgcn_mfma_f32_16x16x32_bf16(a, bf, oac[nt], 0, 0, 0);
        }
    }
    #pragma unroll
    for (int nt = 0; nt < 4; ++nt)
        #pragma unroll
        for (int i = 0; i < 4; ++i) {
            size_t idx = (size_t)(g0 + w*16 + q*4 + i) * 64 + nt*16 + l16;
            out_feat[idx] = b2f(featb[idx]) + oac[nt][i];
        }
}

extern "C" void kernel_launch(void* const* d_in, const int* in_sizes, int n_in,
                              void* d_out, int out_size, void* d_ws, size_t ws_size,
                              hipStream_t stream) {
    const float* feat = (const float*)d_in[0];
    const float* pos  = (const float*)d_in[1];
    const int*   ei   = (const int*)d_in[2];
    const float* deg  = (const float*)d_in[3];
    const int*   cni  = (const int*)d_in[4];
    const float* mask = (const float*)d_in[5];
    const float* W1   = (const float*)d_in[6];
    const float* b1   = (const float*)d_in[7];
    const float* W2   = (const float*)d_in[8];
    const float* b2   = (const float*)d_in[9];
    const float* P1   = (const float*)d_in[10];
    const float* pb1  = (const float*)d_in[11];
    const float* P2   = (const float*)d_in[12];
    const float* pb2  = (const float*)d_in[13];
    const float* U1   = (const float*)d_in[14];
    const float* ub1  = (const float*)d_in[15];
    const float* U2   = (const float*)d_in[16];
    const float* ub2  = (const float*)d_in[17];

    float* out_feat = (float*)d_out;                       // B*C*H
    float* out_pos  = out_feat + (size_t)B_ * C_ * H_;     // B*C*P

    // workspace layout (~35 MB)
    unsigned* descp = (unsigned*)d_ws;                           // B*C*32 uint (128B rows)
    float*  aggf = (float*)(descp + (size_t)B_ * C_ * 32);       // B*C*64 fp32
    float4* ivA  = (float4*)(aggf + (size_t)B_ * C_ * 64);       // B*E float4
    float4* ivR  = ivA + (size_t)B_ * E_;                        // B*E float4
    unsigned short* featb = (unsigned short*)(ivR + (size_t)B_ * E_); // B*C*64
    unsigned short* wbuf  = featb + (size_t)B_ * C_ * 64;        // 28672
    int* cnt    = (int*)(wbuf + WBUF_ELEMS);                     // C
    int* total  = cnt + C_;                                      // 1
    int* cursor = total + 1;                                     // C
    int2* sed   = (int2*)(cursor + C_ + 1);                      // E (8B aligned)

    hipMemsetAsync(cnt, 0, (C_ + 1) * sizeof(int), stream);      // cnt + total

    combo_kernel<<<NB_COMBO, 256, 0, stream>>>(
        W1, W2, P1, U1, U2, wbuf, feat, featb, pos, cni, mask, descp, ei, cnt,
        aggf, out_pos);

    alloc_kernel<<<(C_ + 255) / 256, 256, 0, stream>>>(cnt, cursor, total);

    scatter_kernel<<<(E_ + 255) / 256, 256, 0, stream>>>(ei, cursor, sed);

    geom_kernel<<<(B_ * E_ + 255) / 256, 256, 0, stream>>>(sed, descp, ivA, ivR);

    edge_kernel<<<B_ * ET_, 256, 0, stream>>>(
        featb, sed, ivA, ivR, wbuf, W1, b1, b2, pb1, P2, pb2, aggf, out_pos);

    node_kernel<<<(B_ * C_) / 64, 256, 0, stream>>>(
        featb, aggf, deg, wbuf, ub1, ub2, out_feat);
}

// Round 10
// 210.864 us; speedup vs baseline: 1.0141x; 1.0141x over previous
//
#include <hip/hip_runtime.h>
#include <hip/hip_bf16.h>

#define B_ 2
#define C_ 20000
#define H_ 64
#define M_ 8
#define E_ 200000
#define P_ 3
#define EPS_ 1e-12f
#define ET_ (E_ / 64)   // edge tiles per batch = 3125

typedef __attribute__((ext_vector_type(8))) short short8;
typedef __attribute__((ext_vector_type(4))) float float4v;

// ---- fast approx math (bf16-precision pipeline; absmax tol is huge) -------
__device__ __forceinline__ float rcp_(float x)  { return __builtin_amdgcn_rcpf(x); }
__device__ __forceinline__ float sqrt_(float x) { return __builtin_amdgcn_sqrtf(x); }
__device__ __forceinline__ float silu_(float x) {
    return x * __builtin_amdgcn_rcpf(1.f + __expf(-x));
}
__device__ __forceinline__ float tanh_(float x) {
    // tanh(x) = 1 - 2/(e^{2x}+1); saturates correctly for |x| large
    float e = __expf(2.f * x);
    return 1.f - 2.f * __builtin_amdgcn_rcpf(e + 1.f);
}
__device__ __forceinline__ unsigned short f2b(float f) {
    unsigned u = __float_as_uint(f);
    unsigned r = (u + 0x7FFF + ((u >> 16) & 1)) >> 16;   // RNE fp32->bf16
    return (unsigned short)r;
}
__device__ __forceinline__ float b2f(unsigned short h) {
    return __uint_as_float(((unsigned)h) << 16);
}
__device__ __forceinline__ unsigned pk2u(float a, float b) {
    __hip_bfloat162 h = __float22bfloat162_rn(make_float2(a, b)); // v_cvt_pk_bf16_f32
    unsigned u; __builtin_memcpy(&u, &h, sizeof(u)); return u;
}
__device__ __forceinline__ float lo16f(unsigned u) { return __uint_as_float(u << 16); }
__device__ __forceinline__ float hi16f(unsigned u) { return __uint_as_float(u & 0xFFFF0000u); }

// bf16 B-fragment-swizzled weights (K multiples of 32; W1 rows 128..131 on VALU)
#define W1S_OFF 0
#define W2S_OFF 8192
#define P1S_OFF 12288
#define U1S_OFF 16384
#define U2S_OFF 24576
#define WBUF_ELEMS 28672

// combo_kernel block ranges (all parts independent)
#define NB_PREP  120                     // 28672 weight-frag elems
#define NB_FEATB 2500                    // B*C*64/4 = 640000 threads
#define NB_DESC  157                     // ceil(B*C/256)
#define NB_HIST  782                     // ceil(E/256)
#define NB_ZAGG  2500                    // B*C*64 floats / (256*4) zero-fill
#define NB_PCOPY 118                     // ceil(B*C*3/4 / 256) pos -> out_pos
#define NB_COMBO (NB_PREP + NB_FEATB + NB_DESC + NB_HIST + NB_ZAGG + NB_PCOPY)

// packed descriptor row: 32 uints = 128 B, ONE cache line per (b,cell):
//   u[0..15]  : 8 nodes as uint2{pk(x,y), pk(z,m)}   (bf16)
//   u[16..19] : centroid float4 (cx,cy,cz,summ)      (fp32)
//   u[20..23] : own pos float4 (px,py,pz,0)          (fp32)
//   u[24..31] : pad

__global__ __launch_bounds__(256) void combo_kernel(
    const float* __restrict__ W1, const float* __restrict__ W2,
    const float* __restrict__ P1, const float* __restrict__ U1,
    const float* __restrict__ U2, unsigned short* __restrict__ wbuf,
    const float* __restrict__ feat, unsigned short* __restrict__ featb,
    const float* __restrict__ pos, const int* __restrict__ cni,
    const float* __restrict__ mask, unsigned* __restrict__ descp,
    const int* __restrict__ ei, int* __restrict__ cnt,
    float* __restrict__ aggf, float* __restrict__ out_pos)
{
    const int bid = blockIdx.x;
    if (bid < NB_PREP) {
        // ---- weight swizzle -> bf16 B-fragments
        int t = bid * 256 + threadIdx.x;
        if (t >= WBUF_ELEMS) return;
        const float* W; int e;
        if (t < W2S_OFF)      { W = W1; e = t; }
        else if (t < U1S_OFF) { W = (t < P1S_OFF) ? W2 : P1; e = (t < P1S_OFF) ? t - W2S_OFF : t - P1S_OFF; }
        else if (t < U2S_OFF) { W = U1; e = t - U1S_OFF; }
        else                  { W = U2; e = t - U2S_OFF; }
        int j = e & 7, lane = (e >> 3) & 63, nt = (e >> 9) & 3, kk = e >> 11;
        int k = kk * 32 + ((lane >> 4) * 8) + j;
        int n = nt * 16 + (lane & 15);
        wbuf[t] = f2b(W[k * 64 + n]);
    } else if (bid < NB_PREP + NB_FEATB) {
        // ---- features -> bf16 cache (coalesced)
        int t = (bid - NB_PREP) * 256 + threadIdx.x;   // < 640000 exactly
        float4 v = *(const float4*)&feat[(size_t)t * 4];
        *(uint2*)&featb[(size_t)t * 4] = make_uint2(pk2u(v.x, v.y), pk2u(v.z, v.w));
    } else if (bid < NB_PREP + NB_FEATB + NB_DESC) {
        // ---- per-(b,cell) packed descriptor (one 128B line)
        int tid = (bid - NB_PREP - NB_FEATB) * 256 + threadIdx.x;
        if (tid >= B_ * C_) return;
        int b = tid / C_, c = tid - b * C_;
        const float* pb = pos + (size_t)b * C_ * P_;
        unsigned* D = descp + (size_t)tid * 32;
        int4 n0 = *(const int4*)&cni[c*8];
        int4 n1 = *(const int4*)&cni[c*8 + 4];
        float4 m0 = *(const float4*)&mask[c*8];
        float4 m1 = *(const float4*)&mask[c*8 + 4];
        int ni[8] = {n0.x, n0.y, n0.z, n0.w, n1.x, n1.y, n1.z, n1.w};
        float mm[8] = {m0.x, m0.y, m0.z, m0.w, m1.x, m1.y, m1.z, m1.w};
        float sx = 0.f, sy = 0.f, sz = 0.f, sm = 0.f;
        #pragma unroll
        for (int m = 0; m < 8; ++m) {
            float x = pb[ni[m]*3+0], y = pb[ni[m]*3+1], z = pb[ni[m]*3+2];
            ((uint2*)D)[m] = make_uint2(pk2u(x, y), pk2u(z, mm[m]));
            sx += x * mm[m]; sy += y * mm[m]; sz += z * mm[m]; sm += mm[m];
        }
        float inv = rcp_(fmaxf(sm, EPS_));
        *(float4*)(D + 16) = make_float4(sx * inv, sy * inv, sz * inv, sm);
        *(float4*)(D + 20) = make_float4(pb[c*3+0], pb[c*3+1], pb[c*3+2], 0.f);
    } else if (bid < NB_PREP + NB_FEATB + NB_DESC + NB_HIST) {
        // ---- dst histogram
        int e = (bid - NB_PREP - NB_FEATB - NB_DESC) * 256 + threadIdx.x;
        if (e >= E_) return;
        atomicAdd(&cnt[ei[E_ + e]], 1);
    } else if (bid < NB_PREP + NB_FEATB + NB_DESC + NB_HIST + NB_ZAGG) {
        // ---- zero aggf (consumed only by edge_kernel, later in stream)
        int t = (bid - NB_PREP - NB_FEATB - NB_DESC - NB_HIST) * 256 + threadIdx.x;
        *(float4*)&aggf[(size_t)t * 4] = make_float4(0.f, 0.f, 0.f, 0.f);
    } else {
        // ---- out_pos = pos (base for edge_kernel's atomics)
        int t = (bid - NB_PREP - NB_FEATB - NB_DESC - NB_HIST - NB_ZAGG) * 256 + threadIdx.x;
        if (t >= (B_ * C_ * P_) / 4) return;
        *(float4*)&out_pos[(size_t)t * 4] = *(const float4*)&pos[(size_t)t * 4];
    }
}

// ---------------------------------------------------------------------------
// alloc: wave-scan + one atomic bump per wave -> cursor (segment order free)
// ---------------------------------------------------------------------------
__global__ __launch_bounds__(256) void alloc_kernel(
    const int* __restrict__ cnt, int* __restrict__ cursor, int* __restrict__ total)
{
    int idx = blockIdx.x * 256 + threadIdx.x;
    int lane = threadIdx.x & 63;
    int v = (idx < C_) ? cnt[idx] : 0;
    int inc = v;
    #pragma unroll
    for (int s = 1; s < 64; s <<= 1) {
        int n = __shfl_up(inc, s);
        if (lane >= s) inc += n;
    }
    int wtot = __shfl(inc, 63);
    int base = 0;
    if (lane == 0) base = atomicAdd(total, wtot);
    base = __shfl(base, 0);
    if (idx < C_) cursor[idx] = base + inc - v;
}

// ---------------------------------------------------------------------------
// scatter: plain dst-sort
// ---------------------------------------------------------------------------
__global__ __launch_bounds__(256) void scatter_kernel(
    const int* __restrict__ ei, int* __restrict__ cursor, int2* __restrict__ sed)
{
    int e = blockIdx.x * 256 + threadIdx.x;
    if (e >= E_) return;
    int s = ei[e], d = ei[E_ + e];
    int slot = atomicAdd(&cursor[d], 1);
    sed[slot] = make_int2(s, d);
}

// ---------------------------------------------------------------------------
// Edge kernel with FUSED geometry (packed 1-line desc, quad-j-split, shuffle
// reduce) -> 3 MFMA MLP stages -> in-wave segmented aggregation. No ivA/ivR
// round-trip, no geom launch. 4 waves/block, wave-private LDS arenas
// (18432 B), launch_bounds(256,8) caps VGPR at 64 -> 8 blocks/CU.
// ---------------------------------------------------------------------------
__global__ __launch_bounds__(256, 8) void edge_kernel(
    const unsigned short* __restrict__ featb,
    const int2* __restrict__ sed,
    const unsigned* __restrict__ descp,
    const unsigned short* __restrict__ wbuf, const float* __restrict__ W1,
    const float* __restrict__ b1, const float* __restrict__ b2,
    const float* __restrict__ pb1, const float* __restrict__ P2,
    const float* __restrict__ pb2,
    float* __restrict__ aggf, float* __restrict__ out_pos)
{
    __shared__ unsigned short lds[4 * 2304];   // 18432 B

    const int tid  = threadIdx.x;
    const int w    = tid >> 6;
    const int lane = tid & 63;
    const int q    = lane >> 4;
    const int l16  = lane & 15;
    const int w16  = w * 16;

    // bijective XCD swizzle (nwg = 6250; m204 variant)
    const int bidr = blockIdx.x;
    const int xcd  = bidr & 7, kblk = bidr >> 3;
    const int qq   = (B_ * ET_) >> 3, rr_ = (B_ * ET_) & 7;
    const int tile = (xcd < rr_ ? xcd * (qq + 1) : rr_ * (qq + 1) + (xcd - rr_) * qq) + kblk;

    const int b    = tile / ET_;
    const int i0   = (tile - b * ET_) * 64;
    const unsigned short* fb = featb + (size_t)b * C_ * H_;

    const int2 sd  = sed[i0 + lane];
    const int s_l  = sd.x;
    const int d_l  = sd.y;
    const int sg   = __shfl(s_l, w16 + l16);   // src of row l16
    const int dg   = __shfl(d_l, w16 + l16);   // dst of row l16

    unsigned short* Xw = lds + w * 2304;
    unsigned short* Hw = Xw;          // alias: X dead before H written (dep chain)
    unsigned short* Mw = Xw + 1152;   // disjoint from Hw

    // ================= fused geometry (edge = w16+l16, j-split across quads) =
    const unsigned* Ds = descp + ((size_t)b * C_ + sg) * 32;
    const unsigned* Dd = descp + ((size_t)b * C_ + dg) * 32;
    uint2 spk[8];
    #pragma unroll
    for (int i = 0; i < 8; ++i) spk[i] = ((const uint2*)Ds)[i];
    uint2 dpk[2];
    dpk[0] = ((const uint2*)Dd)[q*2 + 0];
    dpk[1] = ((const uint2*)Dd)[q*2 + 1];
    float4 Sc = *(const float4*)(Ds + 16), Dc = *(const float4*)(Dd + 16);
    float4 Sp = *(const float4*)(Ds + 20), Dp = *(const float4*)(Dd + 20);

    const float INFV = __builtin_inff();
    float4 S[8]; float rowmin[8];
    #pragma unroll
    for (int i = 0; i < 8; ++i) {
        S[i] = make_float4(lo16f(spk[i].x), hi16f(spk[i].x),
                           lo16f(spk[i].y), hi16f(spk[i].y));
        rowmin[i] = INFV;
    }
    float pair = 0.f, hyx = 0.f;
    #pragma unroll
    for (int jj = 0; jj < 2; ++jj) {
        float djx = lo16f(dpk[jj].x), djy = hi16f(dpk[jj].x);
        float djz = lo16f(dpk[jj].y), djw = hi16f(dpk[jj].y);
        float colmin = INFV;
        #pragma unroll
        for (int i = 0; i < 8; ++i) {
            float dx = S[i].x - djx, dy = S[i].y - djy, dz = S[i].z - djz;
            float dd = sqrt_(dx*dx + dy*dy + dz*dz + EPS_);
            pair += dd * S[i].w * djw;
            rowmin[i] = (djw    > 0.f) ? fminf(rowmin[i], dd) : rowmin[i];
            colmin    = (S[i].w > 0.f) ? fminf(colmin, dd)    : colmin;
        }
        hyx = fmaxf(hyx, (djw > 0.f) ? colmin : 0.f);
    }
    pair += __shfl_xor(pair, 16);  pair += __shfl_xor(pair, 32);
    hyx = fmaxf(hyx, __shfl_xor(hyx, 16));  hyx = fmaxf(hyx, __shfl_xor(hyx, 32));
    #pragma unroll
    for (int i = 0; i < 8; ++i) {
        rowmin[i] = fminf(rowmin[i], __shfl_xor(rowmin[i], 16));
        rowmin[i] = fminf(rowmin[i], __shfl_xor(rowmin[i], 32));
    }
    float hxy = 0.f;
    #pragma unroll
    for (int i = 0; i < 8; ++i)
        hxy = fmaxf(hxy, (S[i].w > 0.f) ? rowmin[i] : 0.f);
    float cdx = Sc.x - Dc.x, cdy = Sc.y - Dc.y, cdz = Sc.z - Dc.z;
    const float relx = Sp.x - Dp.x, rely = Sp.y - Dp.y, relz = Sp.z - Dp.z;
    const float ivx = sqrt_(relx*relx + rely*rely + relz*relz);  // dist
    const float ivy = pair;                                      // pairwise
    const float ivz = sqrt_(cdx*cdx + cdy*cdy + cdz*cdz);        // centroid
    const float ivw = fmaxf(hxy, hyx);                           // hausdorff

    // broadcast row invariants to the quad that needs them (rows q*4+i)
    float4 iva[4];
    #pragma unroll
    for (int i = 0; i < 4; ++i) {
        int r = q*4 + i;
        iva[i] = make_float4(__shfl(ivx, r), __shfl(ivy, r),
                             __shfl(ivz, r), __shfl(ivw, r));
    }

    // ================= stage X = [h_src | h_dst] from bf16 cache =============
    const int rr4 = lane >> 4, c4 = lane & 15;
    #pragma unroll
    for (int it = 0; it < 4; ++it) {
        int rloc = it * 4 + rr4;
        int r = w16 + rloc;
        int sr = __shfl(s_l, r);
        int dr = __shfl(d_l, r);
        uint2 vs = *(const uint2*)&fb[(size_t)sr * 64 + c4 * 4];
        uint2 vd = *(const uint2*)&fb[(size_t)dr * 64 + c4 * 4];
        *(uint2*)&Xw[rloc*136 + c4*4]      = vs;
        *(uint2*)&Xw[rloc*136 + 64 + c4*4] = vd;
    }

    // ================= layer 1: bias + fp32 invariant tail folded into init ==
    float4v acc[4];
    #pragma unroll
    for (int nt = 0; nt < 4; ++nt) {
        float bv = b1[nt*16 + l16];
        float wa = W1[128*64 + nt*16 + l16];
        float wb = W1[129*64 + nt*16 + l16];
        float wc = W1[130*64 + nt*16 + l16];
        float wd = W1[131*64 + nt*16 + l16];
        #pragma unroll
        for (int i = 0; i < 4; ++i)
            acc[nt][i] = bv + iva[i].x*wa + iva[i].y*wb
                            + iva[i].z*wc + iva[i].w*wd;
    }
    #pragma unroll
    for (int kk = 0; kk < 4; ++kk) {
        short8 a = *(const short8*)&Xw[l16*136 + kk*32 + q*8];
        #pragma unroll
        for (int nt = 0; nt < 4; ++nt) {
            short8 bf = *(const short8*)&wbuf[W1S_OFF + (((kk*4 + nt)*64) + lane) * 8];
            acc[nt] = __builtin_amdgcn_mfma_f32_16x16x32_bf16(a, bf, acc[nt], 0, 0, 0);
        }
    }
    // packed bf16 epilogue: row-pairs share a v_cvt_pk_bf16_f32
    #pragma unroll
    for (int nt = 0; nt < 4; ++nt)
        #pragma unroll
        for (int i = 0; i < 4; i += 2) {
            unsigned u = pk2u(silu_(acc[nt][i]), silu_(acc[nt][i+1]));
            Hw[(q*4 + i)*72     + nt*16 + l16] = (unsigned short)u;
            Hw[(q*4 + i + 1)*72 + nt*16 + l16] = (unsigned short)(u >> 16);
        }

    // ================= layer 2 -> messages ===================================
    float4v mac[4];
    #pragma unroll
    for (int nt = 0; nt < 4; ++nt) {
        float bv = b2[nt*16 + l16];
        mac[nt] = (float4v){bv, bv, bv, bv};
    }
    #pragma unroll
    for (int kk = 0; kk < 2; ++kk) {
        short8 a = *(const short8*)&Hw[l16*72 + kk*32 + q*8];
        #pragma unroll
        for (int nt = 0; nt < 4; ++nt) {
            short8 bf = *(const short8*)&wbuf[W2S_OFF + (((kk*4 + nt)*64) + lane) * 8];
            mac[nt] = __builtin_amdgcn_mfma_f32_16x16x32_bf16(a, bf, mac[nt], 0, 0, 0);
        }
    }
    #pragma unroll
    for (int nt = 0; nt < 4; ++nt)
        #pragma unroll
        for (int i = 0; i < 4; i += 2) {
            unsigned u = pk2u(mac[nt][i], mac[nt][i+1]);
            Mw[(q*4 + i)*72     + nt*16 + l16] = (unsigned short)u;
            Mw[(q*4 + i + 1)*72 + nt*16 + l16] = (unsigned short)(u >> 16);
        }

    // ================= gate: wt = tanh(silu(M @ P1 + pb1) @ P2 + pb2) ========
    float4v gac[4];
    #pragma unroll
    for (int nt = 0; nt < 4; ++nt) {
        float bv = pb1[nt*16 + l16];
        gac[nt] = (float4v){bv, bv, bv, bv};
    }
    #pragma unroll
    for (int kk = 0; kk < 2; ++kk) {
        short8 a = *(const short8*)&Mw[l16*72 + kk*32 + q*8];
        #pragma unroll
        for (int nt = 0; nt < 4; ++nt) {
            short8 bf = *(const short8*)&wbuf[P1S_OFF + (((kk*4 + nt)*64) + lane) * 8];
            gac[nt] = __builtin_amdgcn_mfma_f32_16x16x32_bf16(a, bf, gac[nt], 0, 0, 0);
        }
    }
    float p2v[4];
    #pragma unroll
    for (int nt = 0; nt < 4; ++nt) p2v[nt] = P2[nt*16 + l16];
    const float pb2v = pb2[0];

    #pragma unroll
    for (int i = 0; i < 4; ++i) {
        float p = 0.f;
        #pragma unroll
        for (int nt = 0; nt < 4; ++nt) p += silu_(gac[nt][i]) * p2v[nt];
        p += __shfl_xor(p, 8);
        p += __shfl_xor(p, 4);
        p += __shfl_xor(p, 2);
        p += __shfl_xor(p, 1);
        float wt = tanh_(p + pb2v);
        // store wt in spare columns 64..65 of the message row (fp32-aligned)
        if (l16 == 0) *(float*)&Mw[(q*4 + i)*72 + 64] = wt;
    }

    // ================= in-wave segmented aggregation =========================
    // Pre-load all 16 message rows (independent LDS reads) + per-row gate.
    float mrow[16];
    #pragma unroll
    for (int rr = 0; rr < 16; ++rr) mrow[rr] = b2f(Mw[rr*72 + lane]);
    float wtl = *(const float*)&Mw[l16*72 + 64];   // lane l16 holds row l16's wt

    float* aggB = aggf + (size_t)b * C_ * 64;
    float* opB  = out_pos + (size_t)b * C_ * 3;

    // full-tile (64-row) boundary ballot: bit l set => segment ends at row l.
    // Row 63 is never a TRUE end (next tile may continue the same dst).
    int dnx = __shfl(d_l, (lane + 1) & 63);
    bool bf64 = (lane == 63) || (d_l != dnx);
    unsigned long long bm64t = __ballot(bf64) & 0x7FFFFFFFFFFFFFFFull;

    // this wave's strip mask (force flush at strip row 15)
    unsigned mask16 = (unsigned)((bm64t >> w16) & 0xFFFFull) | 0x8000u;
    // does the strip's first segment have a TRUE start? (boundary at w16-1)
    const bool head_true = (w16 > 0) && ((bm64t >> (w16 - 1)) & 1ull);

    // distance from row l16 to its segment head (within strip, for the scan)
    unsigned below = mask16 & ((1u << l16) - 1u);
    int dist = l16 - (below ? (31 - __clz((int)below)) : -1) - 1;

    // ---- position update: segmented inclusive scan, per-segment atomics ----
    {
        float sx = wtl * relx, sy = wtl * rely, sz = wtl * relz;
        #pragma unroll
        for (int s = 1; s < 16; s <<= 1) {
            float tx = __shfl_up(sx, s);
            float ty = __shfl_up(sy, s);
            float tz = __shfl_up(sz, s);
            if (dist >= s) { sx += tx; sy += ty; sz += tz; }
        }
        bool bflag = (mask16 >> l16) & 1u;
        if (bflag && q == 0) {          // ~2.6 lanes/wave, 3 atomics each
            float* p = &opB[(size_t)dg * 3];
            atomicAdd(p + 0, sx);
            atomicAdd(p + 1, sy);
            atomicAdd(p + 2, sz);
        }
    }

    // ---- message aggregation: accumulate + flush; private segs use STORES --
    float colacc = 0.f;
    int prev = -1;
    #pragma unroll
    for (int rr = 0; rr < 16; ++rr) {
        colacc += mrow[rr];
        if (mask16 & (1u << rr)) {                         // wave-uniform
            int dseg = __builtin_amdgcn_readlane(dg, rr);  // row rr lives in lane rr
            bool tend   = (bm64t >> (w16 + rr)) & 1ull;    // true segment end here
            bool tstart = (prev >= 0) || head_true;        // true segment start in strip
            if (tend && tstart)
                aggB[(size_t)dseg * 64 + lane] = colacc;   // private: plain store
            else
                atomicAdd(&aggB[(size_t)dseg * 64 + lane], colacc);
            colacc = 0.f;
            prev = rr;
        }
    }
}

// ---------------------------------------------------------------------------
// Node update via MFMA, barrier-free wave-private strips.
// X = [featb | agg/max(deg,1)]; out = b2f(featb) + MLP(X)
// ---------------------------------------------------------------------------
__global__ __launch_bounds__(256, 8) void node_kernel(
    const unsigned short* __restrict__ featb,
    const float* __restrict__ aggf, const float* __restrict__ deg,
    const unsigned short* __restrict__ wbuf,
    const float* __restrict__ ub1, const float* __restrict__ ub2,
    float* __restrict__ out_feat)
{
    __shared__ unsigned short lds[4 * 2304];

    const int tid  = threadIdx.x;
    const int w    = tid >> 6;
    const int lane = tid & 63;
    const int q    = lane >> 4;
    const int l16  = lane & 15;
    const int g0   = blockIdx.x * 64;

    unsigned short* Xw = lds + w * 2304;
    unsigned short* Hw = Xw;          // alias: X dead before H written

    const int rr4 = lane >> 4, c4 = lane & 15;
    #pragma unroll
    for (int it = 0; it < 4; ++it) {
        int rloc = it * 4 + rr4;
        int g = g0 + w*16 + rloc;
        int gc = (g >= C_) ? g - C_ : g;
        float sc = rcp_(fmaxf(deg[gc], 1.f));
        uint2  vf = *(const uint2*)&featb[(size_t)g * 64 + c4 * 4];
        float4 va = *(const float4*)&aggf[(size_t)g * 64 + c4 * 4];
        *(uint2*)&Xw[rloc*136 + c4*4]      = vf;
        *(uint2*)&Xw[rloc*136 + 64 + c4*4] =
            make_uint2(pk2u(va.x*sc, va.y*sc), pk2u(va.z*sc, va.w*sc));
    }

    float4v acc[4];
    #pragma unroll
    for (int nt = 0; nt < 4; ++nt) {
        float bv = ub1[nt*16 + l16];
        acc[nt] = (float4v){bv, bv, bv, bv};
    }
    #pragma unroll
    for (int kk = 0; kk < 4; ++kk) {
        short8 a = *(const short8*)&Xw[l16*136 + kk*32 + q*8];
        #pragma unroll
        for (int nt = 0; nt < 4; ++nt) {
            short8 bf = *(const short8*)&wbuf[U1S_OFF + (((kk*4 + nt)*64) + lane) * 8];
            acc[nt] = __builtin_amdgcn_mfma_f32_16x16x32_bf16(a, bf, acc[nt], 0, 0, 0);
        }
    }
    #pragma unroll
    for (int nt = 0; nt < 4; ++nt)
        #pragma unroll
        for (int i = 0; i < 4; i += 2) {
            unsigned u = pk2u(silu_(acc[nt][i]), silu_(acc[nt][i+1]));
            Hw[(q*4 + i)*72     + nt*16 + l16] = (unsigned short)u;
            Hw[(q*4 + i + 1)*72 + nt*16 + l16] = (unsigned short)(u >> 16);
        }

    float4v oac[4];
    #pragma unroll
    for (int nt = 0; nt < 4; ++nt) {
        float bv = ub2[nt*16 + l16];
        oac[nt] = (float4v){bv, bv, bv, bv};
    }
    #pragma unroll
    for (int kk = 0; kk < 2; ++kk) {
        short8 a = *(const short8*)&Hw[l16*72 + kk*32 + q*8];
        #pragma unroll
        for (int nt = 0; nt < 4; ++nt) {
            short8 bf = *(const short8*)&wbuf[U2S_OFF + (((kk*4 + nt)*64) + lane) * 8];
            oac[nt] = __builtin_amdgcn_mfma_f32_16x16x32_bf16(a, bf, oac[nt], 0, 0, 0);
        }
    }
    #pragma unroll
    for (int nt = 0; nt < 4; ++nt)
        #pragma unroll
        for (int i = 0; i < 4; ++i) {
            size_t idx = (size_t)(g0 + w*16 + q*4 + i) * 64 + nt*16 + l16;
            out_feat[idx] = b2f(featb[idx]) + oac[nt][i];
        }
}

extern "C" void kernel_launch(void* const* d_in, const int* in_sizes, int n_in,
                              void* d_out, int out_size, void* d_ws, size_t ws_size,
                              hipStream_t stream) {
    const float* feat = (const float*)d_in[0];
    const float* pos  = (const float*)d_in[1];
    const int*   ei   = (const int*)d_in[2];
    const float* deg  = (const float*)d_in[3];
    const int*   cni  = (const int*)d_in[4];
    const float* mask = (const float*)d_in[5];
    const float* W1   = (const float*)d_in[6];
    const float* b1   = (const float*)d_in[7];
    const float* W2   = (const float*)d_in[8];
    const float* b2   = (const float*)d_in[9];
    const float* P1   = (const float*)d_in[10];
    const float* pb1  = (const float*)d_in[11];
    const float* P2   = (const float*)d_in[12];
    const float* pb2  = (const float*)d_in[13];
    const float* U1   = (const float*)d_in[14];
    const float* ub1  = (const float*)d_in[15];
    const float* U2   = (const float*)d_in[16];
    const float* ub2  = (const float*)d_in[17];

    float* out_feat = (float*)d_out;                       // B*C*H
    float* out_pos  = out_feat + (size_t)B_ * C_ * H_;     // B*C*P

    // workspace layout (~22 MB)
    unsigned* descp = (unsigned*)d_ws;                           // B*C*32 uint (128B rows)
    float*  aggf = (float*)(descp + (size_t)B_ * C_ * 32);       // B*C*64 fp32
    unsigned short* featb = (unsigned short*)(aggf + (size_t)B_ * C_ * 64); // B*C*64
    unsigned short* wbuf  = featb + (size_t)B_ * C_ * 64;        // 28672
    int* cnt    = (int*)(wbuf + WBUF_ELEMS);                     // C
    int* total  = cnt + C_;                                      // 1
    int* cursor = total + 1;                                     // C
    int2* sed   = (int2*)(cursor + C_ + 1);                      // E (8B aligned)

    hipMemsetAsync(cnt, 0, (C_ + 1) * sizeof(int), stream);      // cnt + total

    combo_kernel<<<NB_COMBO, 256, 0, stream>>>(
        W1, W2, P1, U1, U2, wbuf, feat, featb, pos, cni, mask, descp, ei, cnt,
        aggf, out_pos);

    alloc_kernel<<<(C_ + 255) / 256, 256, 0, stream>>>(cnt, cursor, total);

    scatter_kernel<<<(E_ + 255) / 256, 256, 0, stream>>>(ei, cursor, sed);

    edge_kernel<<<B_ * ET_, 256, 0, stream>>>(
        featb, sed, descp, wbuf, W1, b1, b2, pb1, P2, pb2, aggf, out_pos);

    node_kernel<<<(B_ * C_) / 64, 256, 0, stream>>>(
        featb, aggf, deg, wbuf, ub1, ub2, out_feat);
}